// Round 3
// baseline (120.977 us; speedup 1.0000x reference)
//
#include <hip/hip_runtime.h>
#include <math.h>

#define L_SEQ 2048
#define V 512
#define NROWS 16384
#define LDT 16448          // pT row stride in elements; row bytes = 32896 = 257*128 (128B-aligned rows)
#define NSPLIT 16
#define EPS 1e-10

typedef __bf16 bf16x8 __attribute__((ext_vector_type(8)));
typedef float f32x4 __attribute__((ext_vector_type(4)));

// ---- workspace layout (bytes) ----
// pT     : 512 x LDT bf16 (vocab-major transposed softmax, bf16-rounded)   16,842,752
// gp     : NSPLIT x 512 x 512 fp32 GEMM partials                           16,777,216
// rb     : 23 x 512 fp32 (bf16-rounded boundary rows for corrections)          47,104
// m      : 512 fp32 third-position marginal                                     2,048
// pc     : 1024 x 4 doubles (per-block partials S1,T1,S2,T2)                   32,768
// mp     : 512 x 512 fp32 per-softmaxT-block marginal partials                1 MiB
#define PT_OFF  ((size_t)0)
#define GP_OFF  ((size_t)512 * LDT * 2)
#define RB_OFF  (GP_OFF + (size_t)NSPLIT * V * V * 4)
#define M_OFF   (RB_OFF + (size_t)23 * V * 4)
#define PC_OFF  (M_OFF + (size_t)V * 4)
#define MP_OFF  (PC_OFF + (size_t)1024 * 4 * 8)

#define GLDS16(g, l) __builtin_amdgcn_global_load_lds( \
    (const __attribute__((address_space(1))) unsigned int*)(g), \
    (__attribute__((address_space(3))) unsigned int*)(l), 16, 0, 0)

__device__ __forceinline__ unsigned short f2bf(float f) {
    unsigned u = __float_as_uint(f);
    unsigned r = (u + 0x7fffu + ((u >> 16) & 1u)) >> 16;   // RNE
    return (unsigned short)r;
}

// one wave (64 lanes): sanitize (clamp to +-80) + softmax without
// max-subtraction (exp(<=80)=5.5e34, 512x sum < FLT_MAX) + bf16 RNE round.
__device__ __forceinline__ void softmax_row_bf16(const float* __restrict__ x,
                                                 int lane, unsigned short* out) {
    float4 va = *(const float4*)(x + lane * 4);
    float4 vb = *(const float4*)(x + 256 + lane * 4);
    float v[8] = {va.x, va.y, va.z, va.w, vb.x, vb.y, vb.z, vb.w};
    float e[8];
    float s = 0.0f;
#pragma unroll
    for (int i = 0; i < 8; i++) {
        float xi = fminf(fmaxf(v[i], -80.0f), 80.0f);
        e[i] = __expf(xi);
        s += e[i];
    }
#pragma unroll
    for (int o = 32; o; o >>= 1) s += __shfl_xor(s, o, 64);
    float inv = 1.0f / s;
#pragma unroll
    for (int i = 0; i < 8; i++) out[i] = f2bf(e[i] * inv);
}

// --- fused softmax + bf16 + transpose + marginal partials: 535 blocks -------
__global__ __launch_bounds__(256) void softmaxT_k(const float* __restrict__ in,
                                                  unsigned short* __restrict__ pT,
                                                  float* __restrict__ rb,
                                                  float* __restrict__ mp) {
    __shared__ __align__(16) unsigned short sm[32 * 512];   // 32 KB
    int t = threadIdx.x;
    int w = t >> 6, lane = t & 63;
    if (blockIdx.x >= 512) {
        int j = blockIdx.x - 512;            // 0..22
        if (w == 0) {
            int r = j < 8 ? j * L_SEQ + L_SEQ - 2
                  : j < 16 ? (j - 8) * L_SEQ + L_SEQ - 1
                  : (j - 15) * L_SEQ;
            unsigned short o[8];
            softmax_row_bf16(in + (size_t)r * V, lane, o);
#pragma unroll
            for (int i = 0; i < 4; i++)
                rb[j * V + lane * 4 + i] = __uint_as_float((unsigned)o[i] << 16);
#pragma unroll
            for (int i = 0; i < 4; i++)
                rb[j * V + 256 + lane * 4 + i] = __uint_as_float((unsigned)o[4 + i] << 16);
        }
        return;
    }
    int k0 = blockIdx.x * 32;
#pragma unroll
    for (int i = 0; i < 8; i++) {
        int rr = w * 8 + i;
        unsigned short o[8];
        softmax_row_bf16(in + (size_t)(k0 + rr) * V, lane, o);
        *(ushort4*)&sm[rr * 512 + lane * 4] = make_ushort4(o[0], o[1], o[2], o[3]);
        *(ushort4*)&sm[rr * 512 + 256 + lane * 4] = make_ushort4(o[4], o[5], o[6], o[7]);
    }
    __syncthreads();
    int cA = 2 * t, cB = cA + 1;
    unsigned u[32];
#pragma unroll
    for (int k = 0; k < 32; k++) u[k] = *(const unsigned*)&sm[k * 512 + cA];
    // marginal partials for this block's 32 rows (exclude l=0,1 at seq start)
    bool excl = ((blockIdx.x & 63) == 0);
    float mA = 0.0f, mB = 0.0f;
#pragma unroll
    for (int k = 0; k < 32; k++) {
        if (excl && k < 2) continue;
        mA += __uint_as_float(u[k] << 16);
        mB += __uint_as_float(u[k] & 0xffff0000u);
    }
    *(float2*)&mp[(size_t)blockIdx.x * 512 + cA] = make_float2(mA, mB);
    unsigned oA[16], oB[16];
#pragma unroll
    for (int i = 0; i < 16; i++) {
        unsigned e0 = u[2 * i], e1 = u[2 * i + 1];
        oA[i] = (e0 & 0xffffu) | (e1 << 16);
        oB[i] = (e0 >> 16) | (e1 & 0xffff0000u);
    }
    uint4* dA = (uint4*)(pT + (size_t)cA * LDT + k0);
    uint4* dB = (uint4*)(pT + (size_t)cB * LDT + k0);
#pragma unroll
    for (int i = 0; i < 4; i++) {
        dA[i] = make_uint4(oA[4 * i], oA[4 * i + 1], oA[4 * i + 2], oA[4 * i + 3]);
        dB[i] = make_uint4(oB[4 * i], oB[4 * i + 1], oB[4 * i + 2], oB[4 * i + 3]);
    }
    if (blockIdx.x == 511) {   // zero the 64-element pad tail of both columns
#pragma unroll
        for (int j = 0; j < 8; j++) {
            *(uint4*)(pT + (size_t)cA * LDT + 16384 + 8 * j) = make_uint4(0, 0, 0, 0);
            *(uint4*)(pT + (size_t)cB * LDT + 16384 + 8 * j) = make_uint4(0, 0, 0, 0);
        }
    }
}

// -------- bf16 MFMA GEMM: 128x64 tiles, 16 K-splits of 1024 -----------------
// 512 blocks x 128 threads (2 waves stacked in M, each wave owns a 64x64
// sub-tile = 4x4 frags, 16 MFMA per K=32 step for 8 ds_read_b128).
// Square per-wave tiles cut LDS-read bytes 33% vs the old 64x32 wave tiles
// (6 reads / 8 MFMA) -- gemm is LDS-pipe-bound, not MFMA- or L2-bound.
// XCD-swizzled: XCD x owns splits 2x,2x+1 -> 2.1 MB working set per XCD L2.
// Pipeline: double-buffered LDS; issue GLDS(it+1)+B-reg load first, compute
// cur, ds_write B(it+1), one barrier per iter.
__global__ __launch_bounds__(128) void gemm_k(const unsigned short* __restrict__ pT,
                                              float* __restrict__ gp) {
    __shared__ __align__(16) uint4 ldsA[2][512];   // 2 x 8 KB (128 rows x 32 K)
    __shared__ __align__(16) uint4 ldsB[2][256];   // 2 x 4 KB (64 rows x 32 K)
    int b = blockIdx.x;
    int xcd = b & 7, j = b >> 3;          // j = 0..63
    int split = xcd * 2 + (j >> 5);       // 2 splits per XCD
    int tile = j & 31;                    // 4a x 8b
    int ta = (tile >> 3) * 128, tb = (tile & 7) * 64;
    int t = threadIdx.x, w = t >> 6, lane = t & 63;
    int l15 = lane & 15, q4 = lane >> 4;
    int k0base = split * 1024;

    f32x4 acc[4][4];
#pragma unroll
    for (int g = 0; g < 4; g++)
#pragma unroll
        for (int h = 0; h < 4; h++) acc[g][h] = (f32x4){0.f, 0.f, 0.f, 0.f};

    // A staging: 512 granules, 4 GLDS calls/thread.
    // call c, wave w, lane -> LDS slot 128c + 64w + lane
    //   = row (32c + 16w + lane>>2), quad (lane&3)
    int arow = 16 * w + (lane >> 2);
    int qoffA = (lane & 3) * 8;
    size_t rA[4];
#pragma unroll
    for (int c = 0; c < 4; c++) rA[c] = (size_t)(ta + 32 * c + arow) * LDT;
    // B staging: 256 granules, 2/thread (slots t, 128+t): row s>>2, quad s&3
    int qoffB = (t & 3) * 8;
    const size_t rB0 = (size_t)(tb + (t >> 2)) * LDT;
    const size_t rB1 = (size_t)(tb + 32 + (t >> 2)) * LDT;

#define FUNNEL(dst, x1, y1) do { \
        (dst).x = ((x1).x >> 16) | ((x1).y << 16); \
        (dst).y = ((x1).y >> 16) | ((x1).z << 16); \
        (dst).z = ((x1).z >> 16) | ((x1).w << 16); \
        (dst).w = ((x1).w >> 16) | ((y1) << 16); \
    } while (0)

    // ---- prologue: stage it=0 into buffer 0 ----
    {
        int kel = k0base + qoffA;
        int kelB = k0base + qoffB;
#pragma unroll
        for (int c = 0; c < 4; c++)
            GLDS16(pT + rA[c] + kel, &ldsA[0][128 * c + 64 * w]);
        const unsigned short* g0 = pT + rB0 + kelB;
        const unsigned short* g1 = pT + rB1 + kelB;
        uint4 x0 = *(const uint4*)g0;
        unsigned y0 = *(const unsigned*)(g0 + 8);
        uint4 x1 = *(const uint4*)g1;
        unsigned y1 = *(const unsigned*)(g1 + 8);
        uint4 s0, s1;
        FUNNEL(s0, x0, y0);
        FUNNEL(s1, x1, y1);
        ldsB[0][t] = s0;
        ldsB[0][128 + t] = s1;
        __syncthreads();                  // drains vmcnt+lgkm: buffer 0 ready
    }

    for (int it = 0; it < 32; it++) {
        int cur = it & 1, nxt = cur ^ 1;
        uint4 x0, x1;
        unsigned y0, y1;
        if (it < 31) {                    // issue next tile's loads FIRST
            int kel = k0base + (it + 1) * 32 + qoffA;
            int kelB = k0base + (it + 1) * 32 + qoffB;
#pragma unroll
            for (int c = 0; c < 4; c++)
                GLDS16(pT + rA[c] + kel, &ldsA[nxt][128 * c + 64 * w]);
            const unsigned short* g0 = pT + rB0 + kelB;
            const unsigned short* g1 = pT + rB1 + kelB;
            x0 = *(const uint4*)g0;
            y0 = *(const unsigned*)(g0 + 8);
            x1 = *(const uint4*)g1;
            y1 = *(const unsigned*)(g1 + 8);
        }
        // compute current tile from buf[cur] (no race with nxt-buffer writes)
        bf16x8 af[4], bv[4];
#pragma unroll
        for (int g = 0; g < 4; g++)
            af[g] = __builtin_bit_cast(bf16x8, ldsA[cur][4 * (64 * w + g * 16 + l15) + q4]);
#pragma unroll
        for (int h = 0; h < 4; h++)
            bv[h] = __builtin_bit_cast(bf16x8, ldsB[cur][4 * (h * 16 + l15) + q4]);
#pragma unroll
        for (int g = 0; g < 4; g++)
#pragma unroll
            for (int h = 0; h < 4; h++)
                acc[g][h] = __builtin_amdgcn_mfma_f32_16x16x32_bf16(af[g], bv[h], acc[g][h], 0, 0, 0);
        if (it < 31) {                    // funnel-shift B(it+1) into buf[nxt]
            uint4 s0, s1;
            FUNNEL(s0, x0, y0);
            FUNNEL(s1, x1, y1);
            ldsB[nxt][t] = s0;
            ldsB[nxt][128 + t] = s1;
        }
        __syncthreads();                  // single barrier/iter: buf[nxt] ready
    }
#undef FUNNEL

    // C/D layout: col = lane&15, row = (lane>>4)*4 + reg  [m89/m91]
    float* og = gp + (size_t)split * V * V;
#pragma unroll
    for (int g = 0; g < 4; g++) {
        int a = ta + 64 * w + g * 16 + q4 * 4;
#pragma unroll
        for (int h = 0; h < 4; h++) {
            int b2 = tb + h * 16 + l15;
#pragma unroll
            for (int r = 0; r < 4; r++)
                og[(size_t)(a + r) * V + b2] = acc[g][h][r];
        }
    }
}

// --- fused marginal-reduce + entropy partials: 1040 blocks ------------------
// NOTE: do NOT fuse the final combine in here via a block-ticket. Tried in a
// previous round: every block then needs a device-scope release fence
// (__threadfence) before the ticket atomic, which on 8-XCD MI355X is an L2
// writeback-class op -> reduce_k went 25 -> 72 us (1.8% VALUBusy, gp reads
// pushed out of L2 to HBM). Separate tiny final_k launch is far cheaper.
__global__ __launch_bounds__(256) void reduce_k(const float* __restrict__ mp,
                                                const float* __restrict__ gp,
                                                const float* __restrict__ rb,
                                                float* __restrict__ m,
                                                double* __restrict__ pc) {
    int bid = blockIdx.x, t = threadIdx.x;
    if (bid < 16) {
        int c = bid * 32 + (t & 31);
        int seg = t >> 5;                 // 8 segments of 64 blocks
        float s = 0.0f;
#pragma unroll
        for (int i = 0; i < 64; i++)
            s += mp[(size_t)(seg * 64 + i) * 512 + c];
        __shared__ float redm[8][32];
        redm[seg][t & 31] = s;
        __syncthreads();
        if (t < 32) {
            float acc = 0.0f;
#pragma unroll
            for (int sgi = 0; sgi < 8; sgi++) acc += redm[sgi][t];
            m[bid * 32 + t] = acc;
        }
    } else {
        int idx = (bid - 16) * 256 + t;
        int a = idx >> 9, b = idx & (V - 1);
        double ga = 0, gb2 = 0, gc = 0, gd = 0;
#pragma unroll
        for (int s = 0; s < NSPLIT; s += 4) {
            ga += (double)gp[(size_t)(s + 0) * V * V + idx];
            gb2 += (double)gp[(size_t)(s + 1) * V * V + idx];
            gc += (double)gp[(size_t)(s + 2) * V * V + idx];
            gd += (double)gp[(size_t)(s + 3) * V * V + idx];
        }
        double g = (ga + gb2) + (gc + gd);
        float cross = 0.f, cc = 0.f;
#pragma unroll
        for (int n = 0; n < 7; n++)
            cross = fmaf(rb[(8 + n) * V + a], rb[(16 + n) * V + b], cross);
#pragma unroll
        for (int n = 0; n < 8; n++)
            cc = fmaf(rb[n * V + a], rb[(8 + n) * V + b], cc);
        double g1 = g - (double)cross;     // bigram_joint entry
        double g2 = g1 - (double)cc;       // bi_part entry
        double s1 = g1, t1 = g1 * (double)logf((float)g1);
        double s2 = g2, t2 = g2 * (double)logf((float)g2);
#pragma unroll
        for (int o = 32; o; o >>= 1) {
            s1 += __shfl_xor(s1, o, 64);
            t1 += __shfl_xor(t1, o, 64);
            s2 += __shfl_xor(s2, o, 64);
            t2 += __shfl_xor(t2, o, 64);
        }
        __shared__ double redg[4][4];
        if ((t & 63) == 0) {
            int w = t >> 6;
            redg[w][0] = s1; redg[w][1] = t1; redg[w][2] = s2; redg[w][3] = t2;
        }
        __syncthreads();
        if (t == 0) {
            double* o = pc + (size_t)(bid - 16) * 4;
            o[0] = redg[0][0] + redg[1][0] + redg[2][0] + redg[3][0];
            o[1] = redg[0][1] + redg[1][1] + redg[2][1] + redg[3][1];
            o[2] = redg[0][2] + redg[1][2] + redg[2][2] + redg[3][2];
            o[3] = redg[0][3] + redg[1][3] + redg[2][3] + redg[3][3];
        }
    }
}

// ------------------- final: partial sums + marginal entropy + combine --------
__global__ __launch_bounds__(512) void final_k(const float* __restrict__ m,
                                               const double* __restrict__ pc,
                                               float* __restrict__ out) {
    int t = threadIdx.x;
    double s1 = 0, t1 = 0, s2 = 0, t2 = 0;
#pragma unroll
    for (int j = 0; j < 2; j++) {
        const double* q = pc + (size_t)(t + 512 * j) * 4;
        s1 += q[0]; t1 += q[1]; s2 += q[2]; t2 += q[3];
    }
    double mv = (double)m[t];
    double sm = mv;
    double tm = mv * log(mv);
#pragma unroll
    for (int o = 32; o; o >>= 1) {
        sm += __shfl_xor(sm, o, 64);
        tm += __shfl_xor(tm, o, 64);
        s1 += __shfl_xor(s1, o, 64);
        t1 += __shfl_xor(t1, o, 64);
        s2 += __shfl_xor(s2, o, 64);
        t2 += __shfl_xor(t2, o, 64);
    }
    __shared__ double red[6][8];
    if ((t & 63) == 0) {
        int w = t >> 6;
        red[0][w] = sm; red[1][w] = tm;
        red[2][w] = s1; red[3][w] = t1;
        red[4][w] = s2; red[5][w] = t2;
    }
    __syncthreads();
    if (t == 0) {
        double acc[6];
        for (int i = 0; i < 6; i++) {
            acc[i] = 0;
            for (int w = 0; w < 8; w++) acc[i] += red[i][w];
        }
        double Sm = acc[0], Tm = acc[1];
        double S1 = acc[2], T1 = acc[3], S2 = acc[4], T2 = acc[5];
        double D1 = S1 + EPS;
        double Hbi = (log(D1) * S1 - T1) / D1;
        double mlb = log((double)V * (double)V);
        double cbi = 1.0 - Hbi / (mlb + EPS);
        cbi = fmin(fmax(cbi, 0.0), 1.0);
        double S3 = S2 * Sm;
        double D3 = S3 + EPS;
        double Htri = (log(D3) * S3 - (Sm * T2 + S2 * Tm)) / D3;
        double mlt = log((double)V * (double)V * (double)V);
        double ctri = 1.0 - Htri / (mlt + EPS);
        ctri = fmin(fmax(ctri, 0.0), 1.0);
        double tot = 0.5 * cbi + 0.5 * ctri;
        if (!(tot == tot)) tot = 0.0;
        tot = fmin(fmax(tot, 0.0), 1.0);
        out[0] = (float)tot;
    }
}

extern "C" void kernel_launch(void* const* d_in, const int* in_sizes, int n_in,
                              void* d_out, int out_size, void* d_ws, size_t ws_size,
                              hipStream_t stream) {
    (void)in_sizes; (void)n_in; (void)out_size; (void)ws_size;
    const float* logits = (const float*)d_in[0];
    float* out = (float*)d_out;
    char* ws = (char*)d_ws;
    unsigned short* pT = (unsigned short*)(ws + PT_OFF);
    float* gp = (float*)(ws + GP_OFF);
    float* rb = (float*)(ws + RB_OFF);
    float* m = (float*)(ws + M_OFF);
    double* pc = (double*)(ws + PC_OFF);
    float* mp = (float*)(ws + MP_OFF);

    softmaxT_k<<<535, 256, 0, stream>>>(logits, pT, rb, mp);
    gemm_k<<<512, 128, 0, stream>>>(pT, gp);
    reduce_k<<<1040, 256, 0, stream>>>(mp, gp, rb, m, pc);
    final_k<<<1, 512, 0, stream>>>(m, pc, out);
}

// Round 4
// 112.536 us; speedup vs baseline: 1.0750x; 1.0750x over previous
//
#include <hip/hip_runtime.h>
#include <math.h>

#define L_SEQ 2048
#define V 512
#define NROWS 16384
#define LDT 16448          // pT row stride in elements; row bytes = 32896 = 257*128 (128B-aligned rows)
#define NSPLIT 16
#define EPS 1e-10

// ==== session ledger (do not re-try) ====================================
// R1: reduce->final fusion via block-ticket + __threadfence: reduce_k
//     25 -> 72 us. Device-scope release fence per block is L2-writeback
//     class on 8-XCD MI355X; evicts L2-resident gp. REVERTED.
// R2: gemm double-buffered LDS pipeline: neutral (+1.2 us, within noise).
//     Implicit cross-wave overlap at 8 waves/CU already hides the drain.
// R3: 64x64-per-wave tiles @ 128 thr/block: +6 us. LDS reads -33% but
//     waves/CU 8 -> 4; gemm is latency/occupancy-bound, not LDS-bound.
//     REVERTED to 256-thr 64x32 structure below.
// Top-5 dispatches every round: 2x harness 256MiB workspace fills
// (~44 us each @ 76-78% HBM peak) = ~88 us untouchable floor; our 4
// kernels sum to ~26 us vs ~22-26 us composite memory/launch floor.
// ========================================================================

typedef __bf16 bf16x8 __attribute__((ext_vector_type(8)));
typedef float f32x4 __attribute__((ext_vector_type(4)));

// ---- workspace layout (bytes) ----
// pT     : 512 x LDT bf16 (vocab-major transposed softmax, bf16-rounded)   16,842,752
// gp     : NSPLIT x 512 x 512 fp32 GEMM partials                           16,777,216
// rb     : 23 x 512 fp32 (bf16-rounded boundary rows for corrections)          47,104
// m      : 512 fp32 third-position marginal                                     2,048
// pc     : 1024 x 4 doubles (per-block partials S1,T1,S2,T2)                   32,768
// mp     : 512 x 512 fp32 per-softmaxT-block marginal partials                1 MiB
#define PT_OFF  ((size_t)0)
#define GP_OFF  ((size_t)512 * LDT * 2)
#define RB_OFF  (GP_OFF + (size_t)NSPLIT * V * V * 4)
#define M_OFF   (RB_OFF + (size_t)23 * V * 4)
#define PC_OFF  (M_OFF + (size_t)V * 4)
#define MP_OFF  (PC_OFF + (size_t)1024 * 4 * 8)

#define GLDS16(g, l) __builtin_amdgcn_global_load_lds( \
    (const __attribute__((address_space(1))) unsigned int*)(g), \
    (__attribute__((address_space(3))) unsigned int*)(l), 16, 0, 0)

__device__ __forceinline__ unsigned short f2bf(float f) {
    unsigned u = __float_as_uint(f);
    unsigned r = (u + 0x7fffu + ((u >> 16) & 1u)) >> 16;   // RNE
    return (unsigned short)r;
}

// one wave (64 lanes): sanitize (clamp to +-80) + softmax without
// max-subtraction (exp(<=80)=5.5e34, 512x sum < FLT_MAX) + bf16 RNE round.
__device__ __forceinline__ void softmax_row_bf16(const float* __restrict__ x,
                                                 int lane, unsigned short* out) {
    float4 va = *(const float4*)(x + lane * 4);
    float4 vb = *(const float4*)(x + 256 + lane * 4);
    float v[8] = {va.x, va.y, va.z, va.w, vb.x, vb.y, vb.z, vb.w};
    float e[8];
    float s = 0.0f;
#pragma unroll
    for (int i = 0; i < 8; i++) {
        float xi = fminf(fmaxf(v[i], -80.0f), 80.0f);
        e[i] = __expf(xi);
        s += e[i];
    }
#pragma unroll
    for (int o = 32; o; o >>= 1) s += __shfl_xor(s, o, 64);
    float inv = 1.0f / s;
#pragma unroll
    for (int i = 0; i < 8; i++) out[i] = f2bf(e[i] * inv);
}

// --- fused softmax + bf16 + transpose + marginal partials: 535 blocks -------
__global__ __launch_bounds__(256) void softmaxT_k(const float* __restrict__ in,
                                                  unsigned short* __restrict__ pT,
                                                  float* __restrict__ rb,
                                                  float* __restrict__ mp) {
    __shared__ __align__(16) unsigned short sm[32 * 512];   // 32 KB
    int t = threadIdx.x;
    int w = t >> 6, lane = t & 63;
    if (blockIdx.x >= 512) {
        int j = blockIdx.x - 512;            // 0..22
        if (w == 0) {
            int r = j < 8 ? j * L_SEQ + L_SEQ - 2
                  : j < 16 ? (j - 8) * L_SEQ + L_SEQ - 1
                  : (j - 15) * L_SEQ;
            unsigned short o[8];
            softmax_row_bf16(in + (size_t)r * V, lane, o);
#pragma unroll
            for (int i = 0; i < 4; i++)
                rb[j * V + lane * 4 + i] = __uint_as_float((unsigned)o[i] << 16);
#pragma unroll
            for (int i = 0; i < 4; i++)
                rb[j * V + 256 + lane * 4 + i] = __uint_as_float((unsigned)o[4 + i] << 16);
        }
        return;
    }
    int k0 = blockIdx.x * 32;
#pragma unroll
    for (int i = 0; i < 8; i++) {
        int rr = w * 8 + i;
        unsigned short o[8];
        softmax_row_bf16(in + (size_t)(k0 + rr) * V, lane, o);
        *(ushort4*)&sm[rr * 512 + lane * 4] = make_ushort4(o[0], o[1], o[2], o[3]);
        *(ushort4*)&sm[rr * 512 + 256 + lane * 4] = make_ushort4(o[4], o[5], o[6], o[7]);
    }
    __syncthreads();
    int cA = 2 * t, cB = cA + 1;
    unsigned u[32];
#pragma unroll
    for (int k = 0; k < 32; k++) u[k] = *(const unsigned*)&sm[k * 512 + cA];
    // marginal partials for this block's 32 rows (exclude l=0,1 at seq start)
    bool excl = ((blockIdx.x & 63) == 0);
    float mA = 0.0f, mB = 0.0f;
#pragma unroll
    for (int k = 0; k < 32; k++) {
        if (excl && k < 2) continue;
        mA += __uint_as_float(u[k] << 16);
        mB += __uint_as_float(u[k] & 0xffff0000u);
    }
    *(float2*)&mp[(size_t)blockIdx.x * 512 + cA] = make_float2(mA, mB);
    unsigned oA[16], oB[16];
#pragma unroll
    for (int i = 0; i < 16; i++) {
        unsigned e0 = u[2 * i], e1 = u[2 * i + 1];
        oA[i] = (e0 & 0xffffu) | (e1 << 16);
        oB[i] = (e0 >> 16) | (e1 & 0xffff0000u);
    }
    uint4* dA = (uint4*)(pT + (size_t)cA * LDT + k0);
    uint4* dB = (uint4*)(pT + (size_t)cB * LDT + k0);
#pragma unroll
    for (int i = 0; i < 4; i++) {
        dA[i] = make_uint4(oA[4 * i], oA[4 * i + 1], oA[4 * i + 2], oA[4 * i + 3]);
        dB[i] = make_uint4(oB[4 * i], oB[4 * i + 1], oB[4 * i + 2], oB[4 * i + 3]);
    }
    if (blockIdx.x == 511) {   // zero the 64-element pad tail of both columns
#pragma unroll
        for (int j = 0; j < 8; j++) {
            *(uint4*)(pT + (size_t)cA * LDT + 16384 + 8 * j) = make_uint4(0, 0, 0, 0);
            *(uint4*)(pT + (size_t)cB * LDT + 16384 + 8 * j) = make_uint4(0, 0, 0, 0);
        }
    }
}

// -------- bf16 MFMA GEMM: 128x64 tiles, 16 K-splits of 1024 -----------------
// 512 blocks x 256 threads = 32 tiles (4a x 8b) x 16 splits; XCD-swizzled:
// XCD x owns splits 2x,2x+1 entirely -> 2.1 MB working set per XCD L2.
// 8 waves/CU (2 blocks/CU): cross-wave overlap hides the GLDS drain (R2
// dbuf was neutral; R3 fewer-waves regressed -> keep this exact structure).
// LDS: A 128 rows (8 KB, global_load_lds), B 64 rows (4 KB, funnel-shifted).
__global__ __launch_bounds__(256) void gemm_k(const unsigned short* __restrict__ pT,
                                              float* __restrict__ gp) {
    __shared__ __align__(16) uint4 ldsA[512];
    __shared__ __align__(16) uint4 ldsB[256];
    int b = blockIdx.x;
    int xcd = b & 7, j = b >> 3;          // j = 0..63
    int split = xcd * 2 + (j >> 5);       // 2 splits per XCD
    int tile = j & 31;                    // 4a x 8b
    int ta = (tile >> 3) * 128, tb = (tile & 7) * 64;
    int t = threadIdx.x, w = t >> 6, lane = t & 63;
    int l15 = lane & 15, q = lane >> 4;
    int wa = (w & 1) * 64, wb = (w >> 1) * 32;
    int k0base = split * 1024;

    f32x4 acc[4][2];
#pragma unroll
    for (int g = 0; g < 4; g++)
#pragma unroll
        for (int h = 0; h < 2; h++) acc[g][h] = (f32x4){0.f, 0.f, 0.f, 0.f};

    // A staging: 512 granules, 2/thread (slots 64w+lane, 256+64w+lane)
    int srowA = 16 * w + (lane >> 2);
    int qoffA = (lane & 3) * 8;
    const size_t rA1 = (size_t)(ta + srowA) * LDT;
    const size_t rA2 = (size_t)(ta + 64 + srowA) * LDT;
    // B staging: 256 granules, 1/thread (slot t): row t>>2, quad t&3
    int qoffB = (t & 3) * 8;
    const size_t rB = (size_t)(tb + (t >> 2)) * LDT;

    for (int it = 0; it < 32; it++) {
        int kelA = k0base + it * 32 + qoffA;
        int kelB = k0base + it * 32 + qoffB;
        const unsigned short* gb = pT + rB + kelB;
        uint4 x1 = *(const uint4*)gb;
        unsigned y1 = *(const unsigned*)(gb + 8);
        __syncthreads();                 // prev frag reads done before overwrite
        GLDS16(pT + rA1 + kelA, &ldsA[64 * w]);
        GLDS16(pT + rA2 + kelA, &ldsA[256 + 64 * w]);
        uint4 s1;
        s1.x = (x1.x >> 16) | (x1.y << 16);
        s1.y = (x1.y >> 16) | (x1.z << 16);
        s1.z = (x1.z >> 16) | (x1.w << 16);
        s1.w = (x1.w >> 16) | (y1 << 16);
        ldsB[t] = s1;
        __syncthreads();                 // staging visible (drains vmcnt+lgkm)
        bf16x8 af[4], bv[2];
#pragma unroll
        for (int g = 0; g < 4; g++)
            af[g] = __builtin_bit_cast(bf16x8, ldsA[4 * (wa + g * 16 + l15) + q]);
#pragma unroll
        for (int h = 0; h < 2; h++)
            bv[h] = __builtin_bit_cast(bf16x8, ldsB[4 * (wb + h * 16 + l15) + q]);
#pragma unroll
        for (int g = 0; g < 4; g++)
#pragma unroll
            for (int h = 0; h < 2; h++)
                acc[g][h] = __builtin_amdgcn_mfma_f32_16x16x32_bf16(af[g], bv[h], acc[g][h], 0, 0, 0);
    }

    // C/D layout: col = lane&15, row = (lane>>4)*4 + reg  [m89/m91]
    float* og = gp + (size_t)split * V * V;
#pragma unroll
    for (int g = 0; g < 4; g++) {
        int a = ta + wa + g * 16 + q * 4;
#pragma unroll
        for (int h = 0; h < 2; h++) {
            int b2 = tb + wb + h * 16 + l15;
#pragma unroll
            for (int r = 0; r < 4; r++)
                og[(size_t)(a + r) * V + b2] = acc[g][h][r];
        }
    }
}

// --- fused marginal-reduce + entropy partials: 1040 blocks ------------------
__global__ __launch_bounds__(256) void reduce_k(const float* __restrict__ mp,
                                                const float* __restrict__ gp,
                                                const float* __restrict__ rb,
                                                float* __restrict__ m,
                                                double* __restrict__ pc) {
    int bid = blockIdx.x, t = threadIdx.x;
    if (bid < 16) {
        int c = bid * 32 + (t & 31);
        int seg = t >> 5;                 // 8 segments of 64 blocks
        float s = 0.0f;
#pragma unroll
        for (int i = 0; i < 64; i++)
            s += mp[(size_t)(seg * 64 + i) * 512 + c];
        __shared__ float redm[8][32];
        redm[seg][t & 31] = s;
        __syncthreads();
        if (t < 32) {
            float acc = 0.0f;
#pragma unroll
            for (int sgi = 0; sgi < 8; sgi++) acc += redm[sgi][t];
            m[bid * 32 + t] = acc;
        }
    } else {
        int idx = (bid - 16) * 256 + t;
        int a = idx >> 9, b = idx & (V - 1);
        double ga = 0, gb2 = 0, gc = 0, gd = 0;
#pragma unroll
        for (int s = 0; s < NSPLIT; s += 4) {
            ga += (double)gp[(size_t)(s + 0) * V * V + idx];
            gb2 += (double)gp[(size_t)(s + 1) * V * V + idx];
            gc += (double)gp[(size_t)(s + 2) * V * V + idx];
            gd += (double)gp[(size_t)(s + 3) * V * V + idx];
        }
        double g = (ga + gb2) + (gc + gd);
        float cross = 0.f, cc = 0.f;
#pragma unroll
        for (int n = 0; n < 7; n++)
            cross = fmaf(rb[(8 + n) * V + a], rb[(16 + n) * V + b], cross);
#pragma unroll
        for (int n = 0; n < 8; n++)
            cc = fmaf(rb[n * V + a], rb[(8 + n) * V + b], cc);
        double g1 = g - (double)cross;     // bigram_joint entry
        double g2 = g1 - (double)cc;       // bi_part entry
        double s1 = g1, t1 = g1 * (double)logf((float)g1);
        double s2 = g2, t2 = g2 * (double)logf((float)g2);
#pragma unroll
        for (int o = 32; o; o >>= 1) {
            s1 += __shfl_xor(s1, o, 64);
            t1 += __shfl_xor(t1, o, 64);
            s2 += __shfl_xor(s2, o, 64);
            t2 += __shfl_xor(t2, o, 64);
        }
        __shared__ double redg[4][4];
        if ((t & 63) == 0) {
            int w = t >> 6;
            redg[w][0] = s1; redg[w][1] = t1; redg[w][2] = s2; redg[w][3] = t2;
        }
        __syncthreads();
        if (t == 0) {
            double* o = pc + (size_t)(bid - 16) * 4;
            o[0] = redg[0][0] + redg[1][0] + redg[2][0] + redg[3][0];
            o[1] = redg[0][1] + redg[1][1] + redg[2][1] + redg[3][1];
            o[2] = redg[0][2] + redg[1][2] + redg[2][2] + redg[3][2];
            o[3] = redg[0][3] + redg[1][3] + redg[2][3] + redg[3][3];
        }
    }
}

// ------------------- final: partial sums + marginal entropy + combine --------
__global__ __launch_bounds__(512) void final_k(const float* __restrict__ m,
                                               const double* __restrict__ pc,
                                               float* __restrict__ out) {
    int t = threadIdx.x;
    double s1 = 0, t1 = 0, s2 = 0, t2 = 0;
#pragma unroll
    for (int j = 0; j < 2; j++) {
        const double* q = pc + (size_t)(t + 512 * j) * 4;
        s1 += q[0]; t1 += q[1]; s2 += q[2]; t2 += q[3];
    }
    double mv = (double)m[t];
    double sm = mv;
    double tm = mv * log(mv);
#pragma unroll
    for (int o = 32; o; o >>= 1) {
        sm += __shfl_xor(sm, o, 64);
        tm += __shfl_xor(tm, o, 64);
        s1 += __shfl_xor(s1, o, 64);
        t1 += __shfl_xor(t1, o, 64);
        s2 += __shfl_xor(s2, o, 64);
        t2 += __shfl_xor(t2, o, 64);
    }
    __shared__ double red[6][8];
    if ((t & 63) == 0) {
        int w = t >> 6;
        red[0][w] = sm; red[1][w] = tm;
        red[2][w] = s1; red[3][w] = t1;
        red[4][w] = s2; red[5][w] = t2;
    }
    __syncthreads();
    if (t == 0) {
        double acc[6];
        for (int i = 0; i < 6; i++) {
            acc[i] = 0;
            for (int w = 0; w < 8; w++) acc[i] += red[i][w];
        }
        double Sm = acc[0], Tm = acc[1];
        double S1 = acc[2], T1 = acc[3], S2 = acc[4], T2 = acc[5];
        double D1 = S1 + EPS;
        double Hbi = (log(D1) * S1 - T1) / D1;
        double mlb = log((double)V * (double)V);
        double cbi = 1.0 - Hbi / (mlb + EPS);
        cbi = fmin(fmax(cbi, 0.0), 1.0);
        double S3 = S2 * Sm;
        double D3 = S3 + EPS;
        double Htri = (log(D3) * S3 - (Sm * T2 + S2 * Tm)) / D3;
        double mlt = log((double)V * (double)V * (double)V);
        double ctri = 1.0 - Htri / (mlt + EPS);
        ctri = fmin(fmax(ctri, 0.0), 1.0);
        double tot = 0.5 * cbi + 0.5 * ctri;
        if (!(tot == tot)) tot = 0.0;
        tot = fmin(fmax(tot, 0.0), 1.0);
        out[0] = (float)tot;
    }
}

extern "C" void kernel_launch(void* const* d_in, const int* in_sizes, int n_in,
                              void* d_out, int out_size, void* d_ws, size_t ws_size,
                              hipStream_t stream) {
    (void)in_sizes; (void)n_in; (void)out_size; (void)ws_size;
    const float* logits = (const float*)d_in[0];
    float* out = (float*)d_out;
    char* ws = (char*)d_ws;
    unsigned short* pT = (unsigned short*)(ws + PT_OFF);
    float* gp = (float*)(ws + GP_OFF);
    float* rb = (float*)(ws + RB_OFF);
    float* m = (float*)(ws + M_OFF);
    double* pc = (double*)(ws + PC_OFF);
    float* mp = (float*)(ws + MP_OFF);

    softmaxT_k<<<535, 256, 0, stream>>>(logits, pT, rb, mp);
    gemm_k<<<512, 256, 0, stream>>>(pT, gp);
    reduce_k<<<1040, 256, 0, stream>>>(mp, gp, rb, m, pc);
    final_k<<<1, 512, 0, stream>>>(m, pc, out);
}